// Round 1
// baseline (231.833 us; speedup 1.0000x reference)
//
#include <hip/hip_runtime.h>

#define N_FUNC 10000
#define N_IN   2000
#define N_OUT  2000
#define CCH    8
#define K_FF   16
#define E_TOTAL 170000
#define E_FF    160000   // ff edges: dst[e] = e/16 (structural), src random func
#define E_W1    168000   // ff+if edges (dst < N_FUNC)
#define E_IF    8000
#define BATCH   64
#define N_LAYERS 4
#define EPS_LN  1e-5f
#define IF_CAP  16        // max if-in-degree of a func node (mean 0.8)
#define OUT_CAP 64        // max ff-out-degree (Poisson mean 16; P(>=64) ~ 1e-20)
#define HROW    (BATCH * CCH)   // Hsum row: 512 ushorts (bf16) = 1 KB per node

typedef float f2 __attribute__((ext_vector_type(2)));   // -> v_pk_fma_f32

// ---- bf16 helpers (fp32 math everywhere; RNE on store) ----
__device__ __forceinline__ f2 bfpair(unsigned int u) {   // packed pair -> 2 floats
    f2 r;
    r.x = __builtin_bit_cast(float, u << 16);
    r.y = __builtin_bit_cast(float, u & 0xffff0000u);
    return r;
}
__device__ __forceinline__ unsigned int bfpack2(float f0, float f1) {
    unsigned int x0 = __builtin_bit_cast(unsigned int, f0);
    unsigned int x1 = __builtin_bit_cast(unsigned int, f1);
    unsigned int r0 = (x0 + 0x7fffu + ((x0 >> 16) & 1u)) >> 16;
    unsigned int r1 = (x1 + 0x7fffu + ((x1 >> 16) & 1u)) & 0xffff0000u;
    return r0 | r1;
}

// fast GELU (validated R7: absmax unchanged vs exact erf)
__device__ __forceinline__ float fast_gelu(float x) {
    float x2 = x * x;
    float u  = x * __builtin_fmaf(0.044715f, x2, 1.0f);
    float e  = exp2f(-2.3022080f * u);     // sigmoid(1.5957691*u)
    return x * (1.0f / (1.0f + e));
}

// ---------------- prep: if-edge buckets + out-CSR + needed flags + x transpose ----
// (if_cnt/out_cnt/needed zeroed by one hipMemsetAsync on the stream)

__global__ void fill_prep(const int* __restrict__ src, const int* __restrict__ dst,
                          const float* __restrict__ x,
                          int* __restrict__ if_cnt, int* __restrict__ if_bkt,
                          int* __restrict__ out_cnt, int* __restrict__ out_bkt,
                          int* __restrict__ needed, float* __restrict__ xT) {
    int i = blockIdx.x * blockDim.x + threadIdx.x;
    if (i < E_FF) {                       // CSR of ff edges grouped by src
        int s = src[i];
        int pos = atomicAdd(&out_cnt[s], 1);
        out_bkt[s * OUT_CAP + pos] = i;
    }
    if (i < E_IF) {
        int e = E_FF + i;
        int d = dst[e];
        int pos = atomicAdd(&if_cnt[d], 1);
        if_bkt[d * IF_CAP + pos] = e;
    }
    if (i < N_IN * BATCH) {
        int col = i >> 6, lane = i & 63;
        xT[col * BATCH + lane] = x[lane * N_IN + col];
    }
    if (i < N_OUT) {                      // dst nodes whose h_4 feeds an fo edge
        needed[src[E_W1 + i]] = 1;
    }
}

// ---------------- shared pieces (float2-packed) ----------------

// if-edge contributions: virtual xe value = xT[i] + lf*b3[e]
__device__ __forceinline__ void if_accum(
        f2* __restrict__ acc2, const float* __restrict__ xT,
        const float* __restrict__ w1, const float* __restrict__ b3,
        const int* __restrict__ if_cnt, const int* __restrict__ if_bkt,
        int f, int lane, float lf) {
    int icnt = if_cnt[f];
    for (int j = 0; j < icnt; j++) {
        int e = if_bkt[f * IF_CAP + j];
        int ii = (e - E_FF) >> 2;
        float xv = xT[ii * BATCH + lane] + lf * b3[e];
        f2 xv2; xv2.x = xv; xv2.y = xv;
        const f2* w1v = (const f2*)(w1 + (size_t)e * CCH);
        #pragma unroll
        for (int q = 0; q < 4; q++) acc2[q] += xv2 * w1v[q];
    }
}

__device__ __forceinline__ void ln_gelu(
        const f2* __restrict__ acc2, const float* __restrict__ gamma,
        const float* __restrict__ beta, int f, f2* __restrict__ h2) {
    float mu = 0.f;
    #pragma unroll
    for (int q = 0; q < 4; q++) mu += acc2[q].x + acc2[q].y;
    mu *= 0.125f;
    float var = 0.f;
    #pragma unroll
    for (int q = 0; q < 4; q++) {
        float dx = acc2[q].x - mu, dy = acc2[q].y - mu;
        var += dx * dx + dy * dy;
    }
    var *= 0.125f;
    float rs = rsqrtf(var + EPS_LN);
    const f2* gv = (const f2*)(gamma + (size_t)f * CCH);
    const f2* bv = (const f2*)(beta + (size_t)f * CCH);
    f2 mu2; mu2.x = mu; mu2.y = mu;
    f2 rs2; rs2.x = rs; rs2.y = rs;
    #pragma unroll
    for (int q = 0; q < 4; q++) {
        f2 g = (acc2[q] - mu2) * rs2 * gv[q] + bv[q];
        h2[q].x = fast_gelu(g.x);
        h2[q].y = fast_gelu(g.y);
    }
}

// h computation for node f from materialized edge values v (ff) + if edges
__device__ __forceinline__ void compute_h_from_v(
        const float* __restrict__ v, const float* __restrict__ xT,
        const float* __restrict__ w1, const float* __restrict__ b1,
        const float* __restrict__ gamma, const float* __restrict__ beta,
        const float* __restrict__ b3, const int* __restrict__ if_cnt,
        const int* __restrict__ if_bkt, int f, int lane, float lf,
        f2* __restrict__ h2) {
    // 16 contiguous coalesced 256-B loads (4 KB per wave, streaming)
    float xv[K_FF];
    #pragma unroll
    for (int k = 0; k < K_FF; k++)
        xv[k] = v[(size_t)(f * K_FF + k) * BATCH + lane];

    const f2* b1v = (const f2*)(b1 + (size_t)f * CCH);
    f2 acc2[4];
    #pragma unroll
    for (int q = 0; q < 4; q++) acc2[q] = b1v[q];

    #pragma unroll
    for (int k = 0; k < K_FF; k++) {
        const f2* w1v = (const f2*)(w1 + (size_t)(f * K_FF + k) * CCH);
        f2 xv2; xv2.x = xv[k]; xv2.y = xv[k];
        #pragma unroll
        for (int q = 0; q < 4; q++) acc2[q] += xv2 * w1v[q];
    }
    if_accum(acc2, xT, w1, b3, if_cnt, if_bkt, f, lane, lf);
    ln_gelu(acc2, gamma, beta, f, h2);
}

// ---------------- phase A: materialize ff edge values grouped by src ----------
// v[e][batch] = lf*b3[e] + dot8(w3[e], Hold[src[e]][batch])
// Each Hold row is read exactly ONCE (vs 16x in the gather form).

__global__ __launch_bounds__(256, 4) void edge_vals(
        const unsigned short* __restrict__ Hold, const float* __restrict__ w3,
        const float* __restrict__ b3, const int* __restrict__ out_cnt,
        const int* __restrict__ out_bkt, const int* __restrict__ needed,
        float* __restrict__ v, float lf, int prune) {
    int wid = (blockIdx.x * blockDim.x + threadIdx.x) >> 6;
    int lane = threadIdx.x & 63;
    int s = __builtin_amdgcn_readfirstlane(wid);
    if (s >= N_FUNC) return;
    int cnt = out_cnt[s];
    if (cnt == 0) return;
    uint4 hr = *(const uint4*)(Hold + (size_t)s * HROW + lane * CCH);
    f2 h0 = bfpair(hr.x), h1 = bfpair(hr.y), h2 = bfpair(hr.z), h3 = bfpair(hr.w);
    int base = s * OUT_CAP;
    int e = __builtin_amdgcn_readfirstlane(out_bkt[base]);
    for (int j = 0; j < cnt; j++) {
        // prefetch next bucket entry (scalar) to overlap with w3 load
        int e_nxt = __builtin_amdgcn_readfirstlane(out_bkt[base + j + 1]);
        if (!prune || needed[e >> 4]) {   // e>>4 == dst of ff edge (structural)
            const f2* w3v = (const f2*)(w3 + (size_t)e * CCH);
            f2 d = h0 * w3v[0];
            d += h1 * w3v[1];
            d += h2 * w3v[2];
            d += h3 * w3v[3];
            v[(size_t)e * BATCH + lane] = __builtin_fmaf(lf, b3[e], d.x + d.y);
        }
        e = e_nxt;
    }
}

// ---------------- block 1: xe_0 = 0 on ff edges; Hsum_1 = h_1 ----------------

__global__ __launch_bounds__(256, 4) void block_first(
        unsigned short* __restrict__ Hnew, const float* __restrict__ xT,
        const float* __restrict__ w1, const float* __restrict__ b1,
        const float* __restrict__ gamma, const float* __restrict__ beta,
        const float* __restrict__ b3, const int* __restrict__ if_cnt,
        const int* __restrict__ if_bkt) {
    int wid = (blockIdx.x * blockDim.x + threadIdx.x) >> 6;
    int lane = threadIdx.x & 63;
    int f = __builtin_amdgcn_readfirstlane(wid);
    if (f >= N_FUNC) return;
    const f2* b1v = (const f2*)(b1 + (size_t)f * CCH);
    f2 acc2[4];
    #pragma unroll
    for (int q = 0; q < 4; q++) acc2[q] = b1v[q];
    if_accum(acc2, xT, w1, b3, if_cnt, if_bkt, f, lane, 0.0f);
    f2 h2[4];
    ln_gelu(acc2, gamma, beta, f, h2);
    uint4 o;
    o.x = bfpack2(h2[0].x, h2[0].y); o.y = bfpack2(h2[1].x, h2[1].y);
    o.z = bfpack2(h2[2].x, h2[2].y); o.w = bfpack2(h2[3].x, h2[3].y);
    *(uint4*)(Hnew + (size_t)f * HROW + lane * CCH) = o;
}

// ---------------- blocks 2,3 phase B: streaming v -> h -> Hsum RMW -----------

__global__ __launch_bounds__(256, 4) void block_mid_v(
        const unsigned short* __restrict__ Hold, unsigned short* __restrict__ Hnew,
        const float* __restrict__ v, const float* __restrict__ xT,
        const float* __restrict__ w1, const float* __restrict__ b1,
        const float* __restrict__ gamma, const float* __restrict__ beta,
        const float* __restrict__ b3, const int* __restrict__ if_cnt,
        const int* __restrict__ if_bkt, float lf) {
    int wid = (blockIdx.x * blockDim.x + threadIdx.x) >> 6;
    int lane = threadIdx.x & 63;
    int f = __builtin_amdgcn_readfirstlane(wid);
    if (f >= N_FUNC) return;
    // own row issued early to overlap with v loads
    uint4 own = *(const uint4*)(Hold + (size_t)f * HROW + lane * CCH);
    f2 h2[4];
    compute_h_from_v(v, xT, w1, b1, gamma, beta, b3, if_cnt, if_bkt,
                     f, lane, lf, h2);
    // Hsum_new[f] = Hsum_old[f] + h  (own row, coalesced)
    f2 s0 = bfpair(own.x) + h2[0];
    f2 s1 = bfpair(own.y) + h2[1];
    f2 s2 = bfpair(own.z) + h2[2];
    f2 s3 = bfpair(own.w) + h2[3];
    uint4 o;
    o.x = bfpack2(s0.x, s0.y); o.y = bfpack2(s1.x, s1.y);
    o.z = bfpack2(s2.x, s2.y); o.w = bfpack2(s3.x, s3.y);
    *(uint4*)(Hnew + (size_t)f * HROW + lane * CCH) = o;
}

// ---------------- block 4 + output: only the 2000 fo edges -------------------
// out = xe_4[e]/4 = b3[e] + 0.25 * w3[p] . (Hsum_3[s] + h_4[s]);
// h_4 built from pruned layer-4 edge values.

__global__ __launch_bounds__(256, 4) void block_out_v(
        const unsigned short* __restrict__ Hold, const float* __restrict__ v,
        const float* __restrict__ xT, const float* __restrict__ w1,
        const float* __restrict__ b1, const float* __restrict__ gamma,
        const float* __restrict__ beta, const float* __restrict__ w3,
        const float* __restrict__ b3, const int* __restrict__ esrc,
        const int* __restrict__ if_cnt, const int* __restrict__ if_bkt,
        float* __restrict__ out) {
    int wid = (blockIdx.x * blockDim.x + threadIdx.x) >> 6;   // fo index
    int lane = threadIdx.x & 63;
    int j = __builtin_amdgcn_readfirstlane(wid);
    if (j >= N_OUT) return;
    int e = E_W1 + j;
    int s = __builtin_amdgcn_readfirstlane(esrc[e]);

    uint4 own = *(const uint4*)(Hold + (size_t)s * HROW + lane * CCH);
    f2 h2[4];
    compute_h_from_v(v, xT, w1, b1, gamma, beta, b3, if_cnt, if_bkt,
                     s, lane, 3.0f, h2);
    f2 Hf0 = bfpair(own.x) + h2[0];
    f2 Hf1 = bfpair(own.y) + h2[1];
    f2 Hf2 = bfpair(own.z) + h2[2];
    f2 Hf3 = bfpair(own.w) + h2[3];

    int p = e - E_IF;
    const f2* w3v = (const f2*)(w3 + (size_t)p * CCH);
    f2 a = Hf0 * w3v[0];
    a += Hf1 * w3v[1];
    a += Hf2 * w3v[2];
    a += Hf3 * w3v[3];
    out[lane * N_OUT + j] = b3[e] + 0.25f * (a.x + a.y);
}

// ---------------- launch ----------------

extern "C" void kernel_launch(void* const* d_in, const int* in_sizes, int n_in,
                              void* d_out, int out_size, void* d_ws, size_t ws_size,
                              hipStream_t stream) {
    const float* x      = (const float*)d_in[0];
    const float* w1_val = (const float*)d_in[1];
    const float* b1     = (const float*)d_in[2];
    const float* w3_val = (const float*)d_in[3];
    const float* b3     = (const float*)d_in[4];
    const float* gamma  = (const float*)d_in[5];
    const float* beta   = (const float*)d_in[6];
    const int* edge_src = (const int*)d_in[7];
    const int* edge_dst = (const int*)d_in[8];
    float* out = (float*)d_out;

    char* base = (char*)d_ws;
    size_t off = 0;
    auto alloc = [&](size_t bytes) -> void* {
        void* p = base + off;
        off += (bytes + 255) & ~(size_t)255;
        return p;
    };
    unsigned short* HsumA = (unsigned short*)alloc((size_t)N_FUNC * HROW * 2);  // 10.24 MB bf16
    unsigned short* HsumB = (unsigned short*)alloc((size_t)N_FUNC * HROW * 2);
    float* xT    = (float*)alloc((size_t)N_IN * BATCH * 4);
    int*   cnts  = (int*)alloc((size_t)3 * N_FUNC * 4);   // if_cnt | out_cnt | needed
    int* if_cnt  = cnts;
    int* out_cnt = cnts + N_FUNC;
    int* needed  = cnts + 2 * N_FUNC;
    int* if_bkt  = (int*)alloc((size_t)N_FUNC * IF_CAP * 4);
    int* out_bkt = (int*)alloc((size_t)N_FUNC * OUT_CAP * 4);
    float* v     = (float*)alloc((size_t)E_FF * BATCH * 4);   // 40.96 MB fp32 edge values
    (void)ws_size; (void)in_sizes; (void)n_in; (void)out_size;

    hipMemsetAsync(cnts, 0, (size_t)3 * N_FUNC * 4, stream);   // capture-legal
    fill_prep<<<(E_FF + 255) / 256, 256, 0, stream>>>(
        edge_src, edge_dst, x, if_cnt, if_bkt, out_cnt, out_bkt, needed, xT);

    // block 1: Hsum_1 = h_1 -> A
    block_first<<<(N_FUNC * BATCH) / 256, 256, 0, stream>>>(
        HsumA, xT, w1_val, b1, gamma, beta, b3, if_cnt, if_bkt);

    // block 2: A -> B  (lf = 1)
    edge_vals<<<(N_FUNC * BATCH) / 256, 256, 0, stream>>>(
        HsumA, w3_val, b3, out_cnt, out_bkt, needed, v, 1.0f, 0);
    block_mid_v<<<(N_FUNC * BATCH) / 256, 256, 0, stream>>>(
        HsumA, HsumB, v, xT, w1_val, b1, gamma, beta, b3, if_cnt, if_bkt, 1.0f);

    // block 3: B -> A  (lf = 2)
    edge_vals<<<(N_FUNC * BATCH) / 256, 256, 0, stream>>>(
        HsumB, w3_val, b3, out_cnt, out_bkt, needed, v, 2.0f, 0);
    block_mid_v<<<(N_FUNC * BATCH) / 256, 256, 0, stream>>>(
        HsumB, HsumA, v, xT, w1_val, b1, gamma, beta, b3, if_cnt, if_bkt, 2.0f);

    // block 4 + output: reads Hsum_3 = A  (lf = 3), pruned to needed dsts
    edge_vals<<<(N_FUNC * BATCH) / 256, 256, 0, stream>>>(
        HsumA, w3_val, b3, out_cnt, out_bkt, needed, v, 3.0f, 1);
    block_out_v<<<(N_OUT * BATCH) / 256, 256, 0, stream>>>(
        HsumA, v, xT, w1_val, b1, gamma, beta, w3_val, b3,
        edge_src, if_cnt, if_bkt, out);
}

// Round 2
// 215.193 us; speedup vs baseline: 1.0773x; 1.0773x over previous
//
#include <hip/hip_runtime.h>

#define N_FUNC 10000
#define N_IN   2000
#define N_OUT  2000
#define CCH    8
#define K_FF   16
#define E_TOTAL 170000
#define E_FF    160000   // ff edges: dst[e] = e/16 (structural), src random func
#define E_W1    168000   // ff+if edges (dst < N_FUNC)
#define E_IF    8000
#define BATCH   64
#define N_LAYERS 4
#define EPS_LN  1e-5f
#define IF_CAP  16        // max if-in-degree of a func node (mean 0.8)
#define OUT_CAP 64        // max ff-out-degree (Poisson mean 16; P(>=64) ~ 1e-20)
#define HROW    (BATCH * CCH)   // Hsum row: 512 ushorts (bf16) = 1 KB per node

typedef float f2 __attribute__((ext_vector_type(2)));   // -> v_pk_fma_f32

// ---- bf16 helpers (fp32 math everywhere; RNE on store) ----
__device__ __forceinline__ f2 bfpair(unsigned int u) {   // packed pair -> 2 floats
    f2 r;
    r.x = __builtin_bit_cast(float, u << 16);
    r.y = __builtin_bit_cast(float, u & 0xffff0000u);
    return r;
}
__device__ __forceinline__ unsigned int bfpack2(float f0, float f1) {
    unsigned int x0 = __builtin_bit_cast(unsigned int, f0);
    unsigned int x1 = __builtin_bit_cast(unsigned int, f1);
    unsigned int r0 = (x0 + 0x7fffu + ((x0 >> 16) & 1u)) >> 16;
    unsigned int r1 = (x1 + 0x7fffu + ((x1 >> 16) & 1u)) & 0xffff0000u;
    return r0 | r1;
}
__device__ __forceinline__ unsigned short bf1(float f) {   // single bf16 RNE
    unsigned int x = __builtin_bit_cast(unsigned int, f);
    return (unsigned short)((x + 0x7fffu + ((x >> 16) & 1u)) >> 16);
}
__device__ __forceinline__ float unbf1(unsigned short u) {
    return __builtin_bit_cast(float, (unsigned int)u << 16);
}

// fast GELU (validated R7: absmax unchanged vs exact erf)
__device__ __forceinline__ float fast_gelu(float x) {
    float x2 = x * x;
    float u  = x * __builtin_fmaf(0.044715f, x2, 1.0f);
    float e  = exp2f(-2.3022080f * u);     // sigmoid(1.5957691*u)
    return x * (1.0f / (1.0f + e));
}

// ---------------- prep: if buckets + src-CSR (+pos map) + needed + x transpose
// (if_cnt/out_cnt/needed zeroed by one hipMemsetAsync on the stream)

__global__ void fill_prep(const int* __restrict__ src, const int* __restrict__ dst,
                          const float* __restrict__ x,
                          int* __restrict__ if_cnt, int* __restrict__ if_bkt,
                          int* __restrict__ out_cnt, int* __restrict__ out_bkt,
                          int* __restrict__ pos, int* __restrict__ needed,
                          float* __restrict__ xT) {
    int i = blockIdx.x * blockDim.x + threadIdx.x;
    if (i < E_FF) {                       // CSR of ff edges grouped by src
        int s = src[i];
        int j = atomicAdd(&out_cnt[s], 1);
        int slot = s * OUT_CAP + j;
        out_bkt[slot] = i;                // scattered (prep-only)
        pos[i] = slot;                    // coalesced: i == thread id
    }
    if (i < E_IF) {
        int e = E_FF + i;
        int d = dst[e];
        int p = atomicAdd(&if_cnt[d], 1);
        if_bkt[d * IF_CAP + p] = e;
    }
    if (i < N_IN * BATCH) {
        int col = i >> 6, lane = i & 63;
        xT[col * BATCH + lane] = x[lane * N_IN + col];
    }
    if (i < N_OUT) {                      // dst nodes whose h_4 feeds an fo edge
        needed[src[E_W1 + i]] = 1;
    }
}

// ---------------- shared pieces (float2-packed) ----------------

// if-edge contributions: virtual xe value = xT[i] + lf*b3[e]
__device__ __forceinline__ void if_accum(
        f2* __restrict__ acc2, const float* __restrict__ xT,
        const float* __restrict__ w1, const float* __restrict__ b3,
        const int* __restrict__ if_cnt, const int* __restrict__ if_bkt,
        int f, int lane, float lf) {
    int icnt = if_cnt[f];
    for (int j = 0; j < icnt; j++) {
        int e = if_bkt[f * IF_CAP + j];
        int ii = (e - E_FF) >> 2;
        float xv = xT[ii * BATCH + lane] + lf * b3[e];
        f2 xv2; xv2.x = xv; xv2.y = xv;
        const f2* w1v = (const f2*)(w1 + (size_t)e * CCH);
        #pragma unroll
        for (int q = 0; q < 4; q++) acc2[q] += xv2 * w1v[q];
    }
}

__device__ __forceinline__ void ln_gelu(
        const f2* __restrict__ acc2, const float* __restrict__ gamma,
        const float* __restrict__ beta, int f, f2* __restrict__ h2) {
    float mu = 0.f;
    #pragma unroll
    for (int q = 0; q < 4; q++) mu += acc2[q].x + acc2[q].y;
    mu *= 0.125f;
    float var = 0.f;
    #pragma unroll
    for (int q = 0; q < 4; q++) {
        float dx = acc2[q].x - mu, dy = acc2[q].y - mu;
        var += dx * dx + dy * dy;
    }
    var *= 0.125f;
    float rs = rsqrtf(var + EPS_LN);
    const f2* gv = (const f2*)(gamma + (size_t)f * CCH);
    const f2* bv = (const f2*)(beta + (size_t)f * CCH);
    f2 mu2; mu2.x = mu; mu2.y = mu;
    f2 rs2; rs2.x = rs; rs2.y = rs;
    #pragma unroll
    for (int q = 0; q < 4; q++) {
        f2 g = (acc2[q] - mu2) * rs2 * gv[q] + bv[q];
        h2[q].x = fast_gelu(g.x);
        h2[q].y = fast_gelu(g.y);
    }
}

// h computation for node f from materialized bf16 edge values (via pos map)
__device__ __forceinline__ void compute_h_from_v(
        const unsigned short* __restrict__ vin, const int* __restrict__ pos,
        const float* __restrict__ xT, const float* __restrict__ w1,
        const float* __restrict__ b1, const float* __restrict__ gamma,
        const float* __restrict__ beta, const float* __restrict__ b3,
        const int* __restrict__ if_cnt, const int* __restrict__ if_bkt,
        int f, int lane, float lf, f2* __restrict__ h2) {
    // 16 independent 128-B gathers (bf16, 2 B/lane), all in flight
    float xv[K_FF];
    #pragma unroll
    for (int k = 0; k < K_FF; k++) {
        int slot = __builtin_amdgcn_readfirstlane(pos[f * K_FF + k]);
        xv[k] = unbf1(vin[(size_t)slot * BATCH + lane]);
    }

    const f2* b1v = (const f2*)(b1 + (size_t)f * CCH);
    f2 acc2[4];
    #pragma unroll
    for (int q = 0; q < 4; q++) acc2[q] = b1v[q];

    #pragma unroll
    for (int k = 0; k < K_FF; k++) {
        const f2* w1v = (const f2*)(w1 + (size_t)(f * K_FF + k) * CCH);
        f2 xv2; xv2.x = xv[k]; xv2.y = xv[k];
        #pragma unroll
        for (int q = 0; q < 4; q++) acc2[q] += xv2 * w1v[q];
    }
    if_accum(acc2, xT, w1, b3, if_cnt, if_bkt, f, lane, lf);
    ln_gelu(acc2, gamma, beta, f, h2);
}

// producer tail: this wave holds the NEW fp32 Hsum row of node f in Hf[4];
// emit next-layer edge values for all out-edges, stored contiguously in the
// wave's own CSR region (streaming writes, no scatter).
__device__ __forceinline__ void emit_v(
        const f2* __restrict__ Hf, const float* __restrict__ w3,
        const float* __restrict__ b3, const int* __restrict__ out_cnt,
        const int* __restrict__ out_bkt, const int* __restrict__ needed,
        unsigned short* __restrict__ vout, int f, int lane, float lfn, int prune) {
    int cnt = __builtin_amdgcn_readfirstlane(out_cnt[f]);
    int base = f * OUT_CAP;
    for (int j = 0; j < cnt; j++) {
        int e = __builtin_amdgcn_readfirstlane(out_bkt[base + j]);
        if (prune && !needed[e >> 4]) continue;   // e>>4 == dst (structural)
        const f2* w3v = (const f2*)(w3 + (size_t)e * CCH);
        f2 d = Hf[0] * w3v[0];
        d += Hf[1] * w3v[1];
        d += Hf[2] * w3v[2];
        d += Hf[3] * w3v[3];
        vout[(size_t)(base + j) * BATCH + lane] =
            bf1(__builtin_fmaf(lfn, b3[e], d.x + d.y));
    }
}

// ---------------- block 1: xe_0 = 0 on ff edges; Hsum_1 = h_1; emit v_2 ------

__global__ __launch_bounds__(256, 4) void block_first(
        unsigned short* __restrict__ Hnew, unsigned short* __restrict__ vout,
        const float* __restrict__ xT, const float* __restrict__ w1,
        const float* __restrict__ b1, const float* __restrict__ gamma,
        const float* __restrict__ beta, const float* __restrict__ w3,
        const float* __restrict__ b3, const int* __restrict__ if_cnt,
        const int* __restrict__ if_bkt, const int* __restrict__ out_cnt,
        const int* __restrict__ out_bkt) {
    int wid = (blockIdx.x * blockDim.x + threadIdx.x) >> 6;
    int lane = threadIdx.x & 63;
    int f = __builtin_amdgcn_readfirstlane(wid);
    if (f >= N_FUNC) return;
    const f2* b1v = (const f2*)(b1 + (size_t)f * CCH);
    f2 acc2[4];
    #pragma unroll
    for (int q = 0; q < 4; q++) acc2[q] = b1v[q];
    if_accum(acc2, xT, w1, b3, if_cnt, if_bkt, f, lane, 0.0f);
    f2 h2[4];
    ln_gelu(acc2, gamma, beta, f, h2);
    uint4 o;
    o.x = bfpack2(h2[0].x, h2[0].y); o.y = bfpack2(h2[1].x, h2[1].y);
    o.z = bfpack2(h2[2].x, h2[2].y); o.w = bfpack2(h2[3].x, h2[3].y);
    *(uint4*)(Hnew + (size_t)f * HROW + lane * CCH) = o;
    emit_v(h2, w3, b3, out_cnt, out_bkt, (const int*)0, vout, f, lane, 1.0f, 0);
}

// ---------------- blocks 2,3: v gather -> h -> Hsum RMW -> emit next v ------

__global__ __launch_bounds__(256, 4) void block_mid(
        const unsigned short* __restrict__ Hold, unsigned short* __restrict__ Hnew,
        const unsigned short* __restrict__ vin, unsigned short* __restrict__ vout,
        const int* __restrict__ pos, const float* __restrict__ xT,
        const float* __restrict__ w1, const float* __restrict__ b1,
        const float* __restrict__ gamma, const float* __restrict__ beta,
        const float* __restrict__ w3, const float* __restrict__ b3,
        const int* __restrict__ if_cnt, const int* __restrict__ if_bkt,
        const int* __restrict__ out_cnt, const int* __restrict__ out_bkt,
        const int* __restrict__ needed, float lf, int prune) {
    int wid = (blockIdx.x * blockDim.x + threadIdx.x) >> 6;
    int lane = threadIdx.x & 63;
    int f = __builtin_amdgcn_readfirstlane(wid);
    if (f >= N_FUNC) return;
    // own row issued early to overlap with v gathers
    uint4 own = *(const uint4*)(Hold + (size_t)f * HROW + lane * CCH);
    f2 h2[4];
    compute_h_from_v(vin, pos, xT, w1, b1, gamma, beta, b3, if_cnt, if_bkt,
                     f, lane, lf, h2);
    // Hsum_new[f] = Hsum_old[f] + h  (own row, coalesced)
    f2 Hf[4];
    Hf[0] = bfpair(own.x) + h2[0];
    Hf[1] = bfpair(own.y) + h2[1];
    Hf[2] = bfpair(own.z) + h2[2];
    Hf[3] = bfpair(own.w) + h2[3];
    uint4 o;
    o.x = bfpack2(Hf[0].x, Hf[0].y); o.y = bfpack2(Hf[1].x, Hf[1].y);
    o.z = bfpack2(Hf[2].x, Hf[2].y); o.w = bfpack2(Hf[3].x, Hf[3].y);
    *(uint4*)(Hnew + (size_t)f * HROW + lane * CCH) = o;
    emit_v(Hf, w3, b3, out_cnt, out_bkt, needed, vout, f, lane, lf + 1.0f, prune);
}

// ---------------- block 4 + output: only the 2000 fo edges -------------------
// out = xe_4[e]/4 = b3[e] + 0.25 * w3[p] . (Hsum_3[s] + h_4[s]);
// h_4 built from (pruned) layer-4 edge values.

__global__ __launch_bounds__(256, 4) void block_out(
        const unsigned short* __restrict__ Hold, const unsigned short* __restrict__ vin,
        const int* __restrict__ pos, const float* __restrict__ xT,
        const float* __restrict__ w1, const float* __restrict__ b1,
        const float* __restrict__ gamma, const float* __restrict__ beta,
        const float* __restrict__ w3, const float* __restrict__ b3,
        const int* __restrict__ esrc, const int* __restrict__ if_cnt,
        const int* __restrict__ if_bkt, float* __restrict__ out) {
    int wid = (blockIdx.x * blockDim.x + threadIdx.x) >> 6;   // fo index
    int lane = threadIdx.x & 63;
    int j = __builtin_amdgcn_readfirstlane(wid);
    if (j >= N_OUT) return;
    int e = E_W1 + j;
    int s = __builtin_amdgcn_readfirstlane(esrc[e]);

    uint4 own = *(const uint4*)(Hold + (size_t)s * HROW + lane * CCH);
    f2 h2[4];
    compute_h_from_v(vin, pos, xT, w1, b1, gamma, beta, b3, if_cnt, if_bkt,
                     s, lane, 3.0f, h2);
    f2 Hf0 = bfpair(own.x) + h2[0];
    f2 Hf1 = bfpair(own.y) + h2[1];
    f2 Hf2 = bfpair(own.z) + h2[2];
    f2 Hf3 = bfpair(own.w) + h2[3];

    int p = e - E_IF;
    const f2* w3v = (const f2*)(w3 + (size_t)p * CCH);
    f2 a = Hf0 * w3v[0];
    a += Hf1 * w3v[1];
    a += Hf2 * w3v[2];
    a += Hf3 * w3v[3];
    out[lane * N_OUT + j] = b3[e] + 0.25f * (a.x + a.y);
}

// ---------------- launch ----------------

extern "C" void kernel_launch(void* const* d_in, const int* in_sizes, int n_in,
                              void* d_out, int out_size, void* d_ws, size_t ws_size,
                              hipStream_t stream) {
    const float* x      = (const float*)d_in[0];
    const float* w1_val = (const float*)d_in[1];
    const float* b1     = (const float*)d_in[2];
    const float* w3_val = (const float*)d_in[3];
    const float* b3     = (const float*)d_in[4];
    const float* gamma  = (const float*)d_in[5];
    const float* beta   = (const float*)d_in[6];
    const int* edge_src = (const int*)d_in[7];
    const int* edge_dst = (const int*)d_in[8];
    float* out = (float*)d_out;

    char* base = (char*)d_ws;
    size_t off = 0;
    auto alloc = [&](size_t bytes) -> void* {
        void* p = base + off;
        off += (bytes + 255) & ~(size_t)255;
        return p;
    };
    unsigned short* HsumA = (unsigned short*)alloc((size_t)N_FUNC * HROW * 2);  // 10.24 MB bf16
    unsigned short* HsumB = (unsigned short*)alloc((size_t)N_FUNC * HROW * 2);
    float* xT    = (float*)alloc((size_t)N_IN * BATCH * 4);
    int*   cnts  = (int*)alloc((size_t)3 * N_FUNC * 4);   // if_cnt | out_cnt | needed
    int* if_cnt  = cnts;
    int* out_cnt = cnts + N_FUNC;
    int* needed  = cnts + 2 * N_FUNC;
    int* if_bkt  = (int*)alloc((size_t)N_FUNC * IF_CAP * 4);
    int* out_bkt = (int*)alloc((size_t)N_FUNC * OUT_CAP * 4);
    int* pos     = (int*)alloc((size_t)E_FF * 4);
    // bf16 edge values, src-grouped padded layout, double-buffered (81.92 MB ea)
    unsigned short* vA = (unsigned short*)alloc((size_t)N_FUNC * OUT_CAP * BATCH * 2);
    unsigned short* vB = (unsigned short*)alloc((size_t)N_FUNC * OUT_CAP * BATCH * 2);
    (void)ws_size; (void)in_sizes; (void)n_in; (void)out_size;

    hipMemsetAsync(cnts, 0, (size_t)3 * N_FUNC * 4, stream);   // capture-legal
    fill_prep<<<(E_FF + 255) / 256, 256, 0, stream>>>(
        edge_src, edge_dst, x, if_cnt, if_bkt, out_cnt, out_bkt, pos, needed, xT);

    // block 1: Hsum_1 = h_1 -> A ; emit v_2 -> vA
    block_first<<<(N_FUNC * BATCH) / 256, 256, 0, stream>>>(
        HsumA, vA, xT, w1_val, b1, gamma, beta, w3_val, b3,
        if_cnt, if_bkt, out_cnt, out_bkt);

    // block 2: A -> B (lf = 1); consume vA, emit v_3 -> vB
    block_mid<<<(N_FUNC * BATCH) / 256, 256, 0, stream>>>(
        HsumA, HsumB, vA, vB, pos, xT, w1_val, b1, gamma, beta, w3_val, b3,
        if_cnt, if_bkt, out_cnt, out_bkt, needed, 1.0f, 0);

    // block 3: B -> A (lf = 2); consume vB, emit pruned v_4 -> vA
    block_mid<<<(N_FUNC * BATCH) / 256, 256, 0, stream>>>(
        HsumB, HsumA, vB, vA, pos, xT, w1_val, b1, gamma, beta, w3_val, b3,
        if_cnt, if_bkt, out_cnt, out_bkt, needed, 2.0f, 1);

    // block 4 + output: reads Hsum_3 = A and pruned v_4 = vA (lf = 3)
    block_out<<<(N_OUT * BATCH) / 256, 256, 0, stream>>>(
        HsumA, vA, pos, xT, w1_val, b1, gamma, beta, w3_val, b3,
        edge_src, if_cnt, if_bkt, out);
}